// Round 13
// baseline (3129.053 us; speedup 1.0000x reference)
//
#include <hip/hip_runtime.h>

#define NBATCH 64
#define NS     128
#define ND     256

typedef unsigned long long u64;

static __device__ __forceinline__ float fexp2(float x){ return __builtin_amdgcn_exp2f(x); }
static __device__ __forceinline__ float frcp (float x){ return __builtin_amdgcn_rcpf(x); }
static __device__ __forceinline__ float fast_exp(float x){ return fexp2(x*1.4426950408889634f); }
static __device__ __forceinline__ float fast_log(float x){ return __builtin_amdgcn_logf(x)*0.6931471805599453f; }
static __device__ __forceinline__ float fast_tanh(float x){
  float e = fexp2(x*2.8853900817779268f);        // e^(2x)
  return 1.0f - 2.0f*frcp(e+1.0f);
}
static __device__ __forceinline__ float fast_sig(float x){
  return frcp(1.0f + fexp2(-1.4426950408889634f*x));
}

// ---- self-tagged u64 exchange (round-12 proven correct on HW) ----
static __device__ __forceinline__ void st64(u64* p, u64 v){
  __hip_atomic_store(p, v, __ATOMIC_RELAXED, __HIP_MEMORY_SCOPE_AGENT);
}
static __device__ __forceinline__ u64 ld64(const u64* p){
  return __hip_atomic_load(p, __ATOMIC_RELAXED, __HIP_MEMORY_SCOPE_AGENT);
}
static __device__ __forceinline__ u64 pk(float v, unsigned tag){
  return ((u64)tag << 32) | (u64)__float_as_uint(v);
}
static __device__ __forceinline__ float upk(u64 w){
  return __uint_as_float((unsigned)w);
}

// ---------- setup kernel 0: Wt[d][h] = W1[h*512 + d]  (d<512, h<256) ----------
__global__ void k_transpose_w1(const float* __restrict__ W1, float* __restrict__ Wt){
  __shared__ float tile[64*65];
  int di = blockIdx.x >> 2;   // 0..7
  int hi = blockIdx.x & 3;    // 0..3
  int tid = threadIdx.x;
  #pragma unroll
  for (int r=0;r<16;++r){
    int lin = tid + r*256;
    int h = lin >> 6, d = lin & 63;
    tile[h*65 + d] = W1[(hi*64+h)*512 + di*64 + d];
  }
  __syncthreads();
  #pragma unroll
  for (int r=0;r<16;++r){
    int lin = tid + r*256;
    int d = lin >> 6, h = lin & 63;
    Wt[(di*64+d)*256 + hi*64 + h] = tile[h*65 + d];
  }
}

// ---------- setup kernel 1: dec0 = mean_s enc ----------
__global__ void k_dec0(const float* __restrict__ enc, float* __restrict__ dec0){
  int b = blockIdx.x, d = threadIdx.x;
  float s = 0.f;
  for (int t=0;t<NS;++t) s += enc[(b*NS+t)*ND + d];
  dec0[b*ND+d] = s * (1.0f/(float)NS);
}

// ---------- setup kernel 2: ep2[b][s][h] = enc_proj + b1 ----------
__global__ void k_encproj(const float* __restrict__ enc, const float* __restrict__ Wt,
                          const float* __restrict__ b1, float* __restrict__ ep2){
  __shared__ float enc_l[8*256];
  int b = blockIdx.x >> 4, sg = blockIdx.x & 15;
  int tid = threadIdx.x;
  #pragma unroll
  for (int r=0;r<8;++r){
    int lin = tid + r*256;
    enc_l[lin] = enc[(b*NS + sg*8)*ND + lin];
  }
  __syncthreads();
  float acc[8];
  float bb = b1[tid];
  #pragma unroll
  for (int k=0;k<8;++k) acc[k] = bb;
  for (int d=0; d<ND; ++d){
    float w = Wt[(ND + d)*ND + tid];           // We^T[d][h], h = tid
    #pragma unroll
    for (int k=0;k<8;++k) acc[k] = fmaf(enc_l[k*256+d], w, acc[k]);
  }
  #pragma unroll
  for (int k=0;k<8;++k)
    ep2[(b*NS + sg*8 + k)*ND + tid] = acc[k];
}

// ---------- main persistent decoder: h-only exchange + owner blocks ----------
// bid <  64 : OWNER (batch bid). Holds full Wq (256x256) in registers across
//             512 threads; polls h_new, computes q, scores, argmax, lp, masks;
//             broadcasts one tagged u64 (chosen) per step.
// bid >= 64 : PRODUCER (pbid = bid-64; beta = pbid>>5, o = pbid&31).
//             Weight-stationary LSTM gate slice (r12 code); posts tagged
//             h_new slices only.
__global__ void __launch_bounds__(512)
k_decode(const float* __restrict__ enc,
         const float* __restrict__ W_ih, const float* __restrict__ W_hh,
         const float* __restrict__ b_ih, const float* __restrict__ b_hh,
         const float* __restrict__ W1,   const float* __restrict__ W2,
         const float* __restrict__ ep2,  const float* __restrict__ dec0,
         u64* __restrict__ hT, u64* __restrict__ cwT,
         float* __restrict__ out)
{
  __shared__ float4 x_swz[8*16*8];                 // producer staging (16 KB)
  __shared__ __align__(16) float h_l[256];
  __shared__ __align__(16) float q_l[256];
  __shared__ __align__(16) float w2_l[256];
  __shared__ float sc_l[128];
  __shared__ float hn_l[64];
  __shared__ int   cw_l[8];
  __shared__ unsigned int msched_l[4];
  __shared__ unsigned int mmask_l[4];

  const int tid = threadIdx.x;
  const int bid = blockIdx.x;

  if (bid < NBATCH){
    // ================= OWNER =================
    const int my_b = bid;
    // full Wq in registers: thread (qi, qh) holds W1[qi][qh*128 .. qh*128+128)
    const int qi = tid >> 1, qh = tid & 1;
    float4 wq_r[32];
    {
      const float4* wsrc = (const float4*)(W1 + (size_t)qi*512 + qh*128);
      #pragma unroll
      for (int i=0;i<32;++i) wq_r[i] = wsrc[i];
    }
    if (tid < 256) w2_l[tid] = W2[tid];
    if (tid < 4){ msched_l[tid] = 0u; mmask_l[tid] = 0xFEFEFEFEu; }
    __syncthreads();

    const float NINF = -__builtin_inff();

    for (int t = 0; t < NS; ++t){
      const unsigned tg = (unsigned)(t+1);
      const int par = (t+1) & 1;
      // ---- poll h_new(t+1): 256 tagged words, 1 per lane, per-wave __all ----
      if (tid < 256){
        const u64* hp = hT + (size_t)par*NBATCH*ND + (size_t)my_b*ND + tid;
        u64 w;
        do { w = ld64(hp); } while (!__all((unsigned)(w >> 32) == tg));
        h_l[tid] = upk(w);
      }
      __syncthreads();                         // B1: h_l ready

      // ---- q = Wq . h (register-stationary) ----
      {
        float acc = 0.f;
        const float4* hv = (const float4*)(h_l + qh*128);
        #pragma unroll
        for (int k=0;k<32;++k){
          float4 h4 = hv[k], wv = wq_r[k];
          acc = fmaf(h4.x, wv.x, acc);
          acc = fmaf(h4.y, wv.y, acc);
          acc = fmaf(h4.z, wv.z, acc);
          acc = fmaf(h4.w, wv.w, acc);
        }
        acc += __shfl_xor(acc, 1);
        if (qh == 0) q_l[qi] = acc;
      }
      __syncthreads();                         // B2: q_l ready

      // ---- scores: thread (s, seg) covers 64 dims; ep2 streamed from L2 ----
      {
        int s = tid >> 2, seg = tid & 3;
        const float4* epv = (const float4*)(ep2 + ((size_t)my_b*NS + s)*ND + seg*64);
        const float4* qv  = (const float4*)(q_l  + seg*64);
        const float4* wv  = (const float4*)(w2_l + seg*64);
        float a = 0.f;
        #pragma unroll
        for (int j=0;j<16;++j){
          float4 e = epv[j], qq = qv[j], ww = wv[j];
          a = fmaf(fast_tanh(e.x + qq.x), ww.x, a);
          a = fmaf(fast_tanh(e.y + qq.y), ww.y, a);
          a = fmaf(fast_tanh(e.z + qq.z), ww.z, a);
          a = fmaf(fast_tanh(e.w + qq.w), ww.w, a);
        }
        a += __shfl_xor(a, 1);
        a += __shfl_xor(a, 2);
        if (seg == 0) sc_l[s] = a;
      }
      __syncthreads();                         // B3: sc_l ready

      // ---- wave 0: masked argmax + lp + mask update + broadcast ----
      if (tid < 64){
        int s0 = tid, s1 = tid + 64;
        unsigned m0 = ((msched_l[s0>>5] | mmask_l[s0>>5]) >> (s0&31)) & 1u;
        unsigned m1 = ((msched_l[s1>>5] | mmask_l[s1>>5]) >> (s1&31)) & 1u;
        float v0 = m0 ? NINF : sc_l[s0];
        float v1 = m1 ? NINF : sc_l[s1];
        float bv = v0; int bi = s0;
        if (v1 > bv){ bv = v1; bi = s1; }
        #pragma unroll
        for (int m=1; m<64; m<<=1){
          float ov = __shfl_xor(bv, m);
          int   oi = __shfl_xor(bi, m);
          if (ov > bv || (ov == bv && oi < bi)){ bv = ov; bi = oi; }
        }
        float term = fast_exp(v0 - bv) + fast_exp(v1 - bv);
        #pragma unroll
        for (int m=1; m<64; m<<=1) term += __shfl_xor(term, m);
        if (tid == 0){
          msched_l[bi>>5] |= (1u << (bi & 31));
          if ((bi & 7) != 7){ int nb = bi+1; mmask_l[nb>>5] &= ~(1u << (nb & 31)); }
          out[my_b*NS + t] = (float)bi;
          out[NBATCH*NS + my_b*NS + t] = -fast_log(term);
          st64(&cwT[my_b], ((u64)tg << 32) | (u64)bi);
        }
      }
      // waves 1..7 drift into the next h-poll; wave 0 catches up at B1.
    }
    return;
  }

  // ================= PRODUCER =================
  const int pbid = bid - NBATCH;
  const int o    = pbid & 31;     // gate d-octet (8 dims)
  const int beta = pbid >> 5;     // batch-octet

  const int tl = tid & 255;       // both halves mirror compute (stores gated)
  const int u  = tl >> 3;         // (dd,g)
  const int ks = tl & 7;          // k-slice
  const int dd = u >> 2;
  const int g  = u & 3;
  const int dglob = o*8 + dd;

  float4 wreg[16];
  {
    const float* src = (ks < 4) ? (W_ih + (size_t)(g*ND + dglob)*ND + ks*64)
                                : (W_hh + (size_t)(g*ND + dglob)*ND + (ks-4)*64);
    const float4* s4 = (const float4*)src;
    #pragma unroll
    for (int i=0;i<16;++i) wreg[i] = s4[i];
  }
  const float bias_r = b_ih[g*ND + dglob] + b_hh[g*ND + dglob];

  float creg[8];
  #pragma unroll
  for (int i=0;i<8;++i) creg[i]=0.f;
  float hreg[16];

  const int blc = tl >> 5;
  const int l32 = tl & 31;
  const int bglob = beta*8 + blc;
  const int kbase = l32*16;

  for (int t = 0; t < NS; ++t){
    // ---- poll chosen(t-1): one tagged word per batch ----
    if (t > 0){
      if (tid < 64){
        const int lane = tid & 7;
        u64 w;
        do { w = ld64(&cwT[beta*8 + lane]); }
        while (!__all((unsigned)(w >> 32) == (unsigned)t));
        if (tid < 8) cw_l[tid] = (int)(w & 0xffu);
      }
    }
    __syncthreads();                           // B1: cw_l ready, x_swz free

    // ---- stage x = [dec_h ; h] ----
    if (kbase < 256){
      const float* dsrc = (t == 0) ? (dec0 + (size_t)bglob*ND)
                                   : (enc + ((size_t)bglob*NS + cw_l[blc])*ND);
      const float4* s4 = (const float4*)dsrc + (kbase>>2);
      #pragma unroll
      for (int j=0;j<4;++j){
        int k = kbase + j*4;
        x_swz[(blc*16 + ((k & 63) >> 2))*8 + (k >> 6)] = s4[j];
      }
    } else if (t == 0){
      #pragma unroll
      for (int j=0;j<4;++j){
        int k = kbase + j*4;
        x_swz[(blc*16 + ((k & 63) >> 2))*8 + (k >> 6)] = make_float4(0.f,0.f,0.f,0.f);
      }
    } else {
      float* xs = (float*)x_swz;
      #pragma unroll
      for (int j=0;j<16;++j){
        int k = kbase + j;
        xs[((blc*16 + ((k&63)>>2))*8 + (k>>6))*4 + (k&3)] = hreg[j];
      }
    }
    __syncthreads();                           // B2

    // ---- gates + cell update (weights in registers; r12 code) ----
    const float4* xb = x_swz + ks;
    #pragma unroll
    for (int bl=0; bl<8; ++bl){
      float acc = 0.f;
      #pragma unroll
      for (int i=0;i<16;++i){
        float4 xv = xb[(bl*16 + i)*8];
        acc = fmaf(xv.x, wreg[i].x, acc);
        acc = fmaf(xv.y, wreg[i].y, acc);
        acc = fmaf(xv.z, wreg[i].z, acc);
        acc = fmaf(xv.w, wreg[i].w, acc);
      }
      acc += __shfl_xor(acc, 1);
      acc += __shfl_xor(acc, 2);
      acc += __shfl_xor(acc, 4);
      acc += bias_r;
      float vf = __shfl_xor(acc, 8);   // f gate (g=1)
      float vg = __shfl_xor(acc, 16);  // g gate (g=2)
      float vo = __shfl_xor(acc, 24);  // o gate (g=3)
      if (g == 0){
        float cn = fast_sig(vf)*creg[bl] + fast_sig(acc)*fast_tanh(vg);
        creg[bl] = cn;
        float hn = fast_sig(vo)*fast_tanh(cn);
        if (ks == 0) hn_l[bl*8 + dd] = hn;
      }
    }
    __syncthreads();                           // B3: hn_l ready

    // ---- post tagged h_new slices (fire-and-forget; the ONLY exchange) ----
    if (tid < 64){
      int bl = tid >> 3, d8 = tid & 7;
      st64(&hT[(size_t)((t+1)&1)*NBATCH*ND + (size_t)(beta*8+bl)*ND + o*8 + d8],
           pk(hn_l[bl*8+d8], (unsigned)(t+1)));
    }

    // ---- prefetch h(t+1) for next staging (overlaps owner's window) ----
    if (t+1 < NS && kbase >= 256){
      const unsigned tg = (unsigned)(t+1);
      const u64* hp = hT + (size_t)((t+1)&1)*NBATCH*ND + (size_t)bglob*ND + (kbase-256);
      u64 w[16]; bool ok = false;
      do {
        #pragma unroll
        for (int j=0;j<16;++j) w[j] = ld64(hp + j);
        bool f = true;
        #pragma unroll
        for (int j=0;j<16;++j) f &= ((unsigned)(w[j] >> 32) == tg);
        ok = f;
      } while (!__all(ok));
      #pragma unroll
      for (int j=0;j<16;++j) hreg[j] = upk(w[j]);
    }
  }
}

extern "C" void kernel_launch(void* const* d_in, const int* in_sizes, int n_in,
                              void* d_out, int out_size, void* d_ws, size_t ws_size,
                              hipStream_t stream){
  const float* enc  = (const float*)d_in[0];
  // d_in[1] = S_seq (fixed job/op pattern; unused)
  const float* W_ih = (const float*)d_in[2];
  const float* W_hh = (const float*)d_in[3];
  const float* b_ih = (const float*)d_in[4];
  const float* b_hh = (const float*)d_in[5];
  const float* W1   = (const float*)d_in[6];
  const float* b1   = (const float*)d_in[7];
  const float* W2   = (const float*)d_in[8];
  // d_in[9] = b2: constant shift, cancels in argmax and log_softmax; unused
  float* out = (float*)d_out;

  // tagged exchange buffers first (one memset clears stale tags per launch)
  u64* hT  = (u64*)d_ws;                                  // [2][64][256]
  u64* cwT = hT + (size_t)2*NBATCH*ND;                    // [64]
  const size_t tag_words = (size_t)2*NBATCH*ND + NBATCH;

  float* ep2  = (float*)(cwT + NBATCH);                   // [64][128][256]
  float* Wt   = ep2 + (size_t)NBATCH*NS*ND;               // [512][256]
  float* dec0 = Wt  + 512*256;                            // [64][256]

  hipMemsetAsync(d_ws, 0, tag_words*sizeof(u64), stream);
  hipLaunchKernelGGL(k_transpose_w1, dim3(32),   dim3(256), 0, stream, W1, Wt);
  hipLaunchKernelGGL(k_dec0,         dim3(64),   dim3(256), 0, stream, enc, dec0);
  hipLaunchKernelGGL(k_encproj,      dim3(1024), dim3(256), 0, stream, enc, Wt, b1, ep2);

  // 320 blocks x 512 threads; co-resident under any packing (<=20KB LDS each).
  hipLaunchKernelGGL(k_decode, dim3(320), dim3(512), 0, stream,
                     enc, W_ih, W_hh, b_ih, b_hh, W1, W2, ep2, dec0,
                     hT, cwT, out);
}